// Round 2
// baseline (156.702 us; speedup 1.0000x reference)
//
#include <hip/hip_runtime.h>
#include <hip/hip_bf16.h>

#define Bn 8
#define Nn 1024
#define Dn 256
#define Hn 4
#define HOn 64
#define Tn 5
#define WTR 80   // WT rows per head: 64 W^T cols + 10 Wa rows + 6 zero pad
#define EDS 128  // ed_lds row stride (words); stride%32==0 -> bank=c0%32, 2 lanes/bank = free

typedef short bf16x8 __attribute__((ext_vector_type(8)));
typedef float f32x4 __attribute__((ext_vector_type(4)));

__device__ __forceinline__ float b2f(unsigned short u) {
    unsigned x = ((unsigned)u) << 16;
    float f;
    __builtin_memcpy(&f, &x, 4);
    return f;
}
__device__ __forceinline__ unsigned bfr(float f) {
    unsigned u;
    __builtin_memcpy(&u, &f, 4);
    return (u + 0x7FFFu + ((u >> 16) & 1u)) >> 16;
}
__device__ __forceinline__ unsigned short f2b(float f) { return (unsigned short)bfr(f); }

__device__ __forceinline__ float fast_exp2(float x) {
#if __has_builtin(__builtin_amdgcn_exp2f)
    return __builtin_amdgcn_exp2f(x);
#else
    float r;
    asm("v_exp_f32 %0, %1" : "=v"(r) : "v"(x));
    return r;
#endif
}

// ---------- fallback: signal "workspace too small" with out = 100.0 ----------
__global__ __launch_bounds__(256) void k_signal(float* __restrict__ out, int n) {
    int i = blockIdx.x * 256 + threadIdx.x;
    if (i < n) out[i] = 100.0f;
}

// ---------- kernel 0: WT [H][80][D] bf16: rows 0-63 = W^T, 64-73 = W.a_src|W.a_dst, 74-79 = 0
__global__ __launch_bounds__(256) void k_transpose_w(const float* __restrict__ W,
                                                     const float* __restrict__ a_src,
                                                     const float* __restrict__ a_dst,
                                                     unsigned short* __restrict__ WT) {
    __shared__ float tile[64][65];
    int h = blockIdx.x >> 2;
    int d0 = (blockIdx.x & 3) * 64;
    int c0 = threadIdx.x & 63;
    int r0 = threadIdx.x >> 6;  // 0..3
#pragma unroll
    for (int r = 0; r < 16; r++) {
        int d = r * 4 + r0;
        tile[d][c0] = W[((size_t)(h * Dn + d0 + d)) * HOn + c0];  // coalesced over e
    }
    __syncthreads();
#pragma unroll
    for (int r = 0; r < 16; r++) {
        int e = r * 4 + r0;
        WT[((size_t)(h * WTR + e)) * Dn + d0 + c0] = f2b(tile[c0][e]);
    }
    for (int t = r0; t < 2 * Tn; t += 4) {
        const float* av = (t < Tn) ? (a_src + (h * Tn + t) * HOn)
                                   : (a_dst + (h * Tn + t - Tn) * HOn);
        float s = 0.f;
#pragma unroll
        for (int e = 0; e < HOn; e++) s += tile[c0][e] * av[e];
        WT[((size_t)(h * WTR + 64 + t)) * Dn + d0 + c0] = f2b(s);
    }
    for (int rr = 74 + r0; rr < WTR; rr += 4)
        WT[((size_t)(h * WTR + rr)) * Dn + d0 + c0] = 0;
}

// ---------- kernel 1: h^T = W^T x X^T via MFMA + adj u8 packing ----------
// R18: e_src/e_dst stored pre-scaled by log2(e) so k_attn's exp is a bare v_exp_f32.
__global__ __launch_bounds__(256) void k_proj(const float* __restrict__ X,
                                              const unsigned short* __restrict__ WT,
                                              const int* __restrict__ adj,
                                              unsigned short* __restrict__ hT,
                                              float* __restrict__ e_src,
                                              float* __restrict__ e_dst,
                                              unsigned* __restrict__ adjp) {
    int tid = threadIdx.x;
    int w = tid >> 6;
    int lane = tid & 63;
    int quad = lane >> 4;
    int l15 = lane & 15;
    int b = blockIdx.x >> 6;
    int i0 = (blockIdx.x & 63) * 16;
    int h = w;
    int bh = b * Hn + h;

    // pack this block's 16 adj rows to u8 (coalesced int4 loads / u32 stores)
    {
        const int* arow = adj + ((size_t)(b * Nn + i0)) * Nn;
        unsigned* aout = adjp + ((size_t)(b * Nn + i0)) * Nn / 4;
#pragma unroll 4
        for (int k = 0; k < 16; k++) {
            int idx = tid + k * 256;
            int4 v = *(const int4*)(arow + (size_t)idx * 4);
            unsigned pk = (unsigned)(v.x & 0xFF) | ((unsigned)(v.y & 0xFF) << 8) |
                          ((unsigned)(v.z & 0xFF) << 16) | ((unsigned)(v.w & 0xFF) << 24);
            aout[idx] = pk;
        }
    }

    bf16x8 Bx[8];
    const float* xf = X + ((size_t)(b * Nn + i0 + l15)) * Dn + quad * 8;
#pragma unroll
    for (int kc = 0; kc < 8; kc++) {
        union { bf16x8 v; unsigned u[4]; } uu;
        const float4* xp = (const float4*)(xf + kc * 32);
        float4 A0 = xp[0], A1 = xp[1];
        __hip_bfloat162 h0 = __float22bfloat162_rn(make_float2(A0.x, A0.y));
        __hip_bfloat162 h1 = __float22bfloat162_rn(make_float2(A0.z, A0.w));
        __hip_bfloat162 h2 = __float22bfloat162_rn(make_float2(A1.x, A1.y));
        __hip_bfloat162 h3 = __float22bfloat162_rn(make_float2(A1.z, A1.w));
        __builtin_memcpy(&uu.u[0], &h0, 4);
        __builtin_memcpy(&uu.u[1], &h1, 4);
        __builtin_memcpy(&uu.u[2], &h2, 4);
        __builtin_memcpy(&uu.u[3], &h3, 4);
        Bx[kc] = uu.v;
    }

    f32x4 acc[5] = {{0.f, 0.f, 0.f, 0.f}, {0.f, 0.f, 0.f, 0.f}, {0.f, 0.f, 0.f, 0.f},
                    {0.f, 0.f, 0.f, 0.f}, {0.f, 0.f, 0.f, 0.f}};
    const unsigned short* wbase = WT + (size_t)h * WTR * Dn;
#pragma unroll
    for (int kc = 0; kc < 8; kc++) {
#pragma unroll
        for (int et = 0; et < 5; et++) {
            bf16x8 Aw = *(const bf16x8*)(wbase + (size_t)(et * 16 + l15) * Dn + kc * 32 + quad * 8);
            acc[et] = __builtin_amdgcn_mfma_f32_16x16x32_bf16(Aw, Bx[kc], acc[et], 0, 0, 0);
        }
    }

#pragma unroll
    for (int et = 0; et < 4; et++) {
#pragma unroll
        for (int reg = 0; reg < 4; reg++) {
            int e = et * 16 + quad * 4 + reg;
            hT[((size_t)bh * HOn + e) * Nn + i0 + l15] = f2b(acc[et][reg]);
        }
    }
#pragma unroll
    for (int reg = 0; reg < 4; reg++) {
        int t = quad * 4 + reg;
        if (t < Tn)
            e_src[((size_t)bh * Tn + t) * Nn + i0 + l15] = acc[4][reg] * 1.4426950408889634f;
        else if (t < 2 * Tn)
            e_dst[((size_t)bh * Tn + (t - Tn)) * Nn + i0 + l15] = acc[4][reg] * 1.4426950408889634f;
    }
}

// ---------- kernel 2: fused attention — R19: chunk-top B-fragment register prefetch ----------
// grid: B * (N/16) = 512 blocks x 512 threads (8 waves); wave = (head = w&3, j-half = w>>2).
// R19 theory: R18 left all pipes <=21% (VALU 20, LDS ~20, MFMA 4, HBM 8) at 34% occupancy
// -> latency-serialization. Culprit 1: VGPR=52 forced the PV loop to load 4 hT b128 frags
// per k-step and waitcnt-stall ~250cy x16 per wave. Fix: issue ALL 16 Bf loads at chunk
// top; pass-1 (hundreds of cycles of VALU/LDS) covers the L2 latency. +64 VGPR -> ~116,
// under the 128 cliff so 2 blocks/CU (16 waves) is preserved. Culprit 2: R18's ed skew
// math was wrong (bank = 6a + c0w, collides across a; conflicts 411k -> 2.71M). Fix:
// EDS=128 (stride%32==0 -> bank=c0%32, exactly 2 lanes/bank = free per m136), skew gone.
// Kept: no min-waves (R7 spill); rolled chunk loop (R8 spill); sentinel rows (R18);
// l via 5th MFMA tile (R13); u8 L2-resident adj (R16); grid/block shape optimum (R17).
__global__ __launch_bounds__(512) void k_attn(const unsigned char* __restrict__ adjp,
                                              const float* __restrict__ e_src,
                                              const float* __restrict__ e_dst,
                                              const unsigned short* __restrict__ hT,
                                              const float* __restrict__ bias,
                                              const float* __restrict__ gamma,
                                              const float* __restrict__ beta,
                                              float* __restrict__ out) {
    __shared__ __align__(16) unsigned short p_lds[8][16][136];  // 34,816 B
    __shared__ float es2[4][16][8];                             // [hh][row][a], a=0 -> 0.0
    __shared__ float l_lds[8][16];
    __shared__ __align__(16) float ed_lds[8][6 * EDS];          // per-wave, row 0 sentinel
    float* macc = (float*)&p_lds[4][0][0];  // [4 hh][16 r][64 e] f32 overlay (16,384 B)

    int tid = threadIdx.x;
    int w = tid >> 6;
    int lane = tid & 63;
    int quad = lane >> 4;
    int l15 = lane & 15;
    int hh = w & 3;
    int half = w >> 2;
    int b = blockIdx.x >> 6;
    int i0 = (blockIdx.x & 63) * 16;
    int bh = b * Hn + hh;
    int J0 = half * 512;

    const unsigned char* adj_base = adjp + ((size_t)(b * Nn + i0)) * Nn + J0;
    const float* edst = e_dst + (size_t)bh * Tn * Nn + J0;
    const unsigned short* hTb = hT + (size_t)bh * HOn * Nn;

    int c0 = 2 * lane;
    float* edw = &ed_lds[w][0];

    f32x4 acc[4] = {{0.f, 0.f, 0.f, 0.f}, {0.f, 0.f, 0.f, 0.f},
                    {0.f, 0.f, 0.f, 0.f}, {0.f, 0.f, 0.f, 0.f}};
    f32x4 accl = {0.f, 0.f, 0.f, 0.f};  // l row-sums via MFMA with B = ones
    bf16x8 ONES;
    {
        short o = (short)0x3F80;  // bf16 1.0
        ONES = (bf16x8){o, o, o, o, o, o, o, o};
    }

    // ed sentinel row (a = 0): exp2(-3e38 * anything-leaky) == 0 -> masked p = 0
    edw[c0] = -3e38f;
    edw[c0 + 1] = -3e38f;

    // prefetch adj rows 0-3 of chunk 0 (u16 = 2 adj bytes per lane) + ed chunk 0 regs
    unsigned bufA[4], bufB[4];
#pragma unroll
    for (int r = 0; r < 4; r++)
        bufA[r] = *(const unsigned short*)(adj_base + (size_t)r * Nn + c0);
    float2 edr[Tn];
#pragma unroll
    for (int t = 0; t < Tn; t++) edr[t] = *(const float2*)(edst + t * Nn + c0);

    // es2[hh][row][a] staging (waves 0-3): slot 0 = 0.0 sentinel, slots 1..5 = e_src
    if (w < 4) {
        const float* esrc = e_src + (size_t)bh * Tn * Nn;
#pragma unroll
        for (int idx = lane; idx < 96; idx += 64) {
            int t = idx >> 4, row = idx & 15;
            es2[w][row][t] = t ? esrc[(t - 1) * Nn + i0 + row] : 0.f;
        }
    }
    __syncthreads();

// pass-1: p = exp2(leakyrelu(es2[row][a] + ed_lds[a][col])), sentinels make masked -> 0.
// es: LDS broadcast (6 distinct banks, conflict-free); ed: EDS=128 gather (2-way, free).
#define P1ROW(ROW, AV)                                                          \
    {                                                                           \
        int a0 = (int)((AV) & 0xFFu);                                           \
        int a1 = (int)((AV) >> 8);                                              \
        float e0 = es2[hh][ROW][a0];                                            \
        float e1 = es2[hh][ROW][a1];                                            \
        float d0 = edw[a0 * EDS + c0];                                          \
        float d1 = edw[a1 * EDS + c0 + 1];                                      \
        float x0 = e0 + d0; x0 = fmaxf(x0, 0.01f * x0);                         \
        float x1 = e1 + d1; x1 = fmaxf(x1, 0.01f * x1);                         \
        float p0 = fast_exp2(x0);                                               \
        float p1 = fast_exp2(x1);                                               \
        __hip_bfloat162 pp = __float22bfloat162_rn(make_float2(p0, p1));        \
        unsigned pu; __builtin_memcpy(&pu, &pp, 4);                             \
        *(unsigned*)(&p_lds[w][ROW][2 * lane]) = pu;                            \
    }

#pragma unroll 1
    for (int c = 0; c < 4; c++) {
        int jc = c * 128;  // relative to J0
        // R19: issue ALL of this chunk's PV B-fragments now; consumed after pass-1, so
        // the entire pass-1 phase covers their L2/L3 latency. 16 x b128 = 64 VGPRs.
        bf16x8 Bfr[16];
#pragma unroll
        for (int k = 0; k < 4; k++)
#pragma unroll
            for (int et = 0; et < 4; et++)
                Bfr[k * 4 + et] = *(const bf16x8*)(hTb + (size_t)(et * 16 + l15) * Nn +
                                                   J0 + jc + k * 32 + quad * 8);
        // commit this chunk's ed regs to LDS rows 1..5 (in-order DS keeps prior reads safe)
#pragma unroll
        for (int t = 0; t < Tn; t++) {
            int wi = (t + 1) * EDS + c0;
            edw[wi] = edr[t].x;
            edw[wi + 1] = edr[t].y;
        }
        // rolling 4-row adj buffers (L2 hits, covered by a 4-row pass-1 group)
#pragma unroll
        for (int r = 0; r < 4; r++)
            bufB[r] = *(const unsigned short*)(adj_base + (size_t)(4 + r) * Nn + jc + c0);
#pragma unroll
        for (int r = 0; r < 4; r++) P1ROW(r, bufA[r]);
#pragma unroll
        for (int r = 0; r < 4; r++)
            bufA[r] = *(const unsigned short*)(adj_base + (size_t)(8 + r) * Nn + jc + c0);
        // next chunk's ed prefetch into regs (consumed at next chunk top)
        if (c < 3) {
#pragma unroll
            for (int t = 0; t < Tn; t++)
                edr[t] = *(const float2*)(edst + t * Nn + jc + 128 + c0);
        }
#pragma unroll
        for (int r = 0; r < 4; r++) P1ROW(4 + r, bufB[r]);
#pragma unroll
        for (int r = 0; r < 4; r++)
            bufB[r] = *(const unsigned short*)(adj_base + (size_t)(12 + r) * Nn + jc + c0);
#pragma unroll
        for (int r = 0; r < 4; r++) P1ROW(8 + r, bufA[r]);
        if (c < 3) {
#pragma unroll
            for (int r = 0; r < 4; r++)
                bufA[r] = *(const unsigned short*)(adj_base + (size_t)r * Nn + jc + 128 + c0);
        }
#pragma unroll
        for (int r = 0; r < 4; r++) P1ROW(12 + r, bufB[r]);
        // PV via MFMA: A = P (own-wave LDS, b128); B from prefetched regs; 5th tile = l sums
#pragma unroll
        for (int k = 0; k < 4; k++) {
            bf16x8 Afr = *(const bf16x8*)(&p_lds[w][l15][k * 32 + quad * 8]);
            accl = __builtin_amdgcn_mfma_f32_16x16x32_bf16(Afr, ONES, accl, 0, 0, 0);
#pragma unroll
            for (int et = 0; et < 4; et++)
                acc[et] = __builtin_amdgcn_mfma_f32_16x16x32_bf16(Afr, Bfr[k * 4 + et],
                                                                  acc[et], 0, 0, 0);
        }
    }
#undef P1ROW

    // l: accl[reg] (any l15 col) = row-sum for row quad*4+reg
    if (l15 == 0) {
#pragma unroll
        for (int reg = 0; reg < 4; reg++) l_lds[w][quad * 4 + reg] = accl[reg];
    }
    __syncthreads();  // all waves done with p_lds (MFMA reads) before macc overlay
    if (w >= 4) {
#pragma unroll
        for (int et = 0; et < 4; et++)
#pragma unroll
            for (int reg = 0; reg < 4; reg++)
                macc[((hh * 16) + quad * 4 + reg) * 64 + et * 16 + l15] = acc[et][reg];
    }
    __syncthreads();
    if (w >= 4) return;

    // merge + epilogue: /l, +bias, relu, +h, LayerNorm over HO, store f32
    float bv[4], gv[4], bev[4];
#pragma unroll
    for (int et = 0; et < 4; et++) {
        int e = et * 16 + l15;
        bv[et] = bias[hh * HOn + e];
        gv[et] = gamma[hh * HOn + e];
        bev[et] = beta[hh * HOn + e];
    }
#pragma unroll
    for (int reg = 0; reg < 4; reg++) {
        int r = quad * 4 + reg;
        int i = i0 + r;
        float lw = l_lds[w][r] + l_lds[w + 4][r];
        float linv = 1.f / fmaxf(lw, 1e-30f);
        float dv[4];
        float s = 0.f, ss = 0.f;
#pragma unroll
        for (int et = 0; et < 4; et++) {
            int e = et * 16 + l15;
            float v = (acc[et][reg] + macc[((hh * 16) + r) * 64 + e]) * linv + bv[et];
            v = (v > 0.f) ? v : 0.f;
            v += b2f(hTb[(size_t)e * Nn + i]);  // residual h
            dv[et] = v;
            s += v;
            ss += v * v;
        }
#pragma unroll
        for (int off = 8; off; off >>= 1) {
            s += __shfl_xor(s, off);
            ss += __shfl_xor(ss, off);
        }
        float mean = s * (1.f / 64.f);
        float var = ss * (1.f / 64.f) - mean * mean;
        float rstd = rsqrtf(var + 1e-6f);
#pragma unroll
        for (int et = 0; et < 4; et++) {
            int e = et * 16 + l15;
            float o = (dv[et] - mean) * rstd * gv[et] + bev[et];
            out[((size_t)(b * Nn + i)) * (Hn * HOn) + hh * HOn + e] = o;
        }
    }
}

extern "C" void kernel_launch(void* const* d_in, const int* in_sizes, int n_in,
                              void* d_out, int out_size, void* d_ws, size_t ws_size,
                              hipStream_t stream) {
    const float* X = (const float*)d_in[0];        // nodes_embed f32 [B,N,D]
    const int* adj = (const int*)d_in[1];          // node_adj int32 [B,N,N]
    const float* W = (const float*)d_in[2];        // [H,D,HO] f32
    const float* a_src = (const float*)d_in[3];    // [H,T,HO] f32
    const float* a_dst = (const float*)d_in[4];    // [H,T,HO] f32
    const float* bias = (const float*)d_in[5];     // [H,HO] f32
    const float* gamma = (const float*)d_in[6];    // [H,HO] f32
    const float* beta = (const float*)d_in[7];     // [H,HO] f32
    float* out = (float*)d_out;                    // [B,N,H*HO] f32

    char* ws = (char*)d_ws;
    size_t off = 0;
    unsigned short* hT = (unsigned short*)(ws + off);  off += (size_t)Bn * Hn * Nn * HOn * 2;  // 4 MB
    unsigned short* WT = (unsigned short*)(ws + off);  off += (size_t)Hn * WTR * Dn * 2;       // 160 KB
    float* e_src = (float*)(ws + off);                 off += (size_t)Bn * Hn * Tn * Nn * 4;   // 640 KB
    float* e_dst = (float*)(ws + off);                 off += (size_t)Bn * Hn * Tn * Nn * 4;   // 640 KB
    unsigned char* adjp = (unsigned char*)(ws + off);  off += (size_t)Bn * Nn * Nn;            // 8 MB

    if (ws_size < off) {
        k_signal<<<(out_size + 255) / 256, 256, 0, stream>>>(out, out_size);
        return;
    }

    k_transpose_w<<<Hn * (Dn / 64), 256, 0, stream>>>(W, a_src, a_dst, WT);
    k_proj<<<Bn * (Nn / 16), 256, 0, stream>>>(X, WT, adj, hT, e_src, e_dst, (unsigned*)adjp);
    k_attn<<<Bn * (Nn / 16), 512, 0, stream>>>(adjp, e_src, e_dst, hT, bias, gamma, beta, out);
}

// Round 3
// 149.842 us; speedup vs baseline: 1.0458x; 1.0458x over previous
//
#include <hip/hip_runtime.h>
#include <hip/hip_bf16.h>

#define Bn 8
#define Nn 1024
#define Dn 256
#define Hn 4
#define HOn 64
#define Tn 5
#define WTR 80   // WT rows per head: 64 W^T cols + 10 Wa rows + 6 zero pad
#define EDS 128  // ed_lds row stride (words); stride%32==0 -> bank=c0%32, 2 lanes/bank = free

typedef short bf16x8 __attribute__((ext_vector_type(8)));
typedef float f32x4 __attribute__((ext_vector_type(4)));

__device__ __forceinline__ float b2f(unsigned short u) {
    unsigned x = ((unsigned)u) << 16;
    float f;
    __builtin_memcpy(&f, &x, 4);
    return f;
}
__device__ __forceinline__ unsigned bfr(float f) {
    unsigned u;
    __builtin_memcpy(&u, &f, 4);
    return (u + 0x7FFFu + ((u >> 16) & 1u)) >> 16;
}
__device__ __forceinline__ unsigned short f2b(float f) { return (unsigned short)bfr(f); }

__device__ __forceinline__ float fast_exp2(float x) {
#if __has_builtin(__builtin_amdgcn_exp2f)
    return __builtin_amdgcn_exp2f(x);
#else
    float r;
    asm("v_exp_f32 %0, %1" : "=v"(r) : "v"(x));
    return r;
#endif
}

// ---------- fallback: signal "workspace too small" with out = 100.0 ----------
__global__ __launch_bounds__(256) void k_signal(float* __restrict__ out, int n) {
    int i = blockIdx.x * 256 + threadIdx.x;
    if (i < n) out[i] = 100.0f;
}

// ---------- kernel 0: WT [H][80][D] bf16: rows 0-63 = W^T, 64-73 = W.a_src|W.a_dst, 74-79 = 0
__global__ __launch_bounds__(256) void k_transpose_w(const float* __restrict__ W,
                                                     const float* __restrict__ a_src,
                                                     const float* __restrict__ a_dst,
                                                     unsigned short* __restrict__ WT) {
    __shared__ float tile[64][65];
    int h = blockIdx.x >> 2;
    int d0 = (blockIdx.x & 3) * 64;
    int c0 = threadIdx.x & 63;
    int r0 = threadIdx.x >> 6;  // 0..3
#pragma unroll
    for (int r = 0; r < 16; r++) {
        int d = r * 4 + r0;
        tile[d][c0] = W[((size_t)(h * Dn + d0 + d)) * HOn + c0];  // coalesced over e
    }
    __syncthreads();
#pragma unroll
    for (int r = 0; r < 16; r++) {
        int e = r * 4 + r0;
        WT[((size_t)(h * WTR + e)) * Dn + d0 + c0] = f2b(tile[c0][e]);
    }
    for (int t = r0; t < 2 * Tn; t += 4) {
        const float* av = (t < Tn) ? (a_src + (h * Tn + t) * HOn)
                                   : (a_dst + (h * Tn + t - Tn) * HOn);
        float s = 0.f;
#pragma unroll
        for (int e = 0; e < HOn; e++) s += tile[c0][e] * av[e];
        WT[((size_t)(h * WTR + 64 + t)) * Dn + d0 + c0] = f2b(s);
    }
    for (int rr = 74 + r0; rr < WTR; rr += 4)
        WT[((size_t)(h * WTR + rr)) * Dn + d0 + c0] = 0;
}

// ---------- kernel 1: h^T = W^T x X^T via MFMA + adj u8 packing ----------
// R18: e_src/e_dst stored pre-scaled by log2(e) so k_attn's exp is a bare v_exp_f32.
__global__ __launch_bounds__(256) void k_proj(const float* __restrict__ X,
                                              const unsigned short* __restrict__ WT,
                                              const int* __restrict__ adj,
                                              unsigned short* __restrict__ hT,
                                              float* __restrict__ e_src,
                                              float* __restrict__ e_dst,
                                              unsigned* __restrict__ adjp) {
    int tid = threadIdx.x;
    int w = tid >> 6;
    int lane = tid & 63;
    int quad = lane >> 4;
    int l15 = lane & 15;
    int b = blockIdx.x >> 6;
    int i0 = (blockIdx.x & 63) * 16;
    int h = w;
    int bh = b * Hn + h;

    // pack this block's 16 adj rows to u8 (coalesced int4 loads / u32 stores)
    {
        const int* arow = adj + ((size_t)(b * Nn + i0)) * Nn;
        unsigned* aout = adjp + ((size_t)(b * Nn + i0)) * Nn / 4;
#pragma unroll 4
        for (int k = 0; k < 16; k++) {
            int idx = tid + k * 256;
            int4 v = *(const int4*)(arow + (size_t)idx * 4);
            unsigned pk = (unsigned)(v.x & 0xFF) | ((unsigned)(v.y & 0xFF) << 8) |
                          ((unsigned)(v.z & 0xFF) << 16) | ((unsigned)(v.w & 0xFF) << 24);
            aout[idx] = pk;
        }
    }

    bf16x8 Bx[8];
    const float* xf = X + ((size_t)(b * Nn + i0 + l15)) * Dn + quad * 8;
#pragma unroll
    for (int kc = 0; kc < 8; kc++) {
        union { bf16x8 v; unsigned u[4]; } uu;
        const float4* xp = (const float4*)(xf + kc * 32);
        float4 A0 = xp[0], A1 = xp[1];
        __hip_bfloat162 h0 = __float22bfloat162_rn(make_float2(A0.x, A0.y));
        __hip_bfloat162 h1 = __float22bfloat162_rn(make_float2(A0.z, A0.w));
        __hip_bfloat162 h2 = __float22bfloat162_rn(make_float2(A1.x, A1.y));
        __hip_bfloat162 h3 = __float22bfloat162_rn(make_float2(A1.z, A1.w));
        __builtin_memcpy(&uu.u[0], &h0, 4);
        __builtin_memcpy(&uu.u[1], &h1, 4);
        __builtin_memcpy(&uu.u[2], &h2, 4);
        __builtin_memcpy(&uu.u[3], &h3, 4);
        Bx[kc] = uu.v;
    }

    f32x4 acc[5] = {{0.f, 0.f, 0.f, 0.f}, {0.f, 0.f, 0.f, 0.f}, {0.f, 0.f, 0.f, 0.f},
                    {0.f, 0.f, 0.f, 0.f}, {0.f, 0.f, 0.f, 0.f}};
    const unsigned short* wbase = WT + (size_t)h * WTR * Dn;
#pragma unroll
    for (int kc = 0; kc < 8; kc++) {
#pragma unroll
        for (int et = 0; et < 5; et++) {
            bf16x8 Aw = *(const bf16x8*)(wbase + (size_t)(et * 16 + l15) * Dn + kc * 32 + quad * 8);
            acc[et] = __builtin_amdgcn_mfma_f32_16x16x32_bf16(Aw, Bx[kc], acc[et], 0, 0, 0);
        }
    }

#pragma unroll
    for (int et = 0; et < 4; et++) {
#pragma unroll
        for (int reg = 0; reg < 4; reg++) {
            int e = et * 16 + quad * 4 + reg;
            hT[((size_t)bh * HOn + e) * Nn + i0 + l15] = f2b(acc[et][reg]);
        }
    }
#pragma unroll
    for (int reg = 0; reg < 4; reg++) {
        int t = quad * 4 + reg;
        if (t < Tn)
            e_src[((size_t)bh * Tn + t) * Nn + i0 + l15] = acc[4][reg] * 1.4426950408889634f;
        else if (t < 2 * Tn)
            e_dst[((size_t)bh * Tn + (t - Tn)) * Nn + i0 + l15] = acc[4][reg] * 1.4426950408889634f;
    }
}

// ---------- kernel 2: fused attention — R20: full-chunk adj register prefetch ----------
// grid: B * (N/16) = 512 blocks x 512 threads (8 waves); wave = (head = w&3, j-half = w>>2).
// R20: R19's 16-frag Bf prefetch REVERTED (compiler refused the +64 VGPR, sank the loads,
// dur 43.8->52.4; per-k Bf loads restored — measured best). Kept EDS=128 (conflicts
// 2.71M->1.46M, residual ~= benign 2-way). New: adj rolling 4-row buffers (only ~120cy
// cover vs 300-900cy adjp L2-miss latency) replaced by FULL-CHUNK prefetch: all 16 rows
// of chunk c+1 issued at top of chunk c -> a whole chunk (~600+cy) of latency cover.
// +32 VGPR (adjC+adjN) -> ~84, under the 128 cliff; waves/SIMD >= 4 preserved.
// Kept: no min-waves (R7 spill); rolled chunk loop (R8 spill); sentinel rows + LDS-gather
// pass-1 (R18); l via 5th MFMA tile (R13); u8 adj (R16); grid/block shape optimum (R17).
__global__ __launch_bounds__(512) void k_attn(const unsigned char* __restrict__ adjp,
                                              const float* __restrict__ e_src,
                                              const float* __restrict__ e_dst,
                                              const unsigned short* __restrict__ hT,
                                              const float* __restrict__ bias,
                                              const float* __restrict__ gamma,
                                              const float* __restrict__ beta,
                                              float* __restrict__ out) {
    __shared__ __align__(16) unsigned short p_lds[8][16][136];  // 34,816 B
    __shared__ float es2[4][16][8];                             // [hh][row][a], a=0 -> 0.0
    __shared__ float l_lds[8][16];
    __shared__ __align__(16) float ed_lds[8][6 * EDS];          // per-wave, row 0 sentinel
    float* macc = (float*)&p_lds[4][0][0];  // [4 hh][16 r][64 e] f32 overlay (16,384 B)

    int tid = threadIdx.x;
    int w = tid >> 6;
    int lane = tid & 63;
    int quad = lane >> 4;
    int l15 = lane & 15;
    int hh = w & 3;
    int half = w >> 2;
    int b = blockIdx.x >> 6;
    int i0 = (blockIdx.x & 63) * 16;
    int bh = b * Hn + hh;
    int J0 = half * 512;

    const unsigned char* adj_base = adjp + ((size_t)(b * Nn + i0)) * Nn + J0;
    const float* edst = e_dst + (size_t)bh * Tn * Nn + J0;
    const unsigned short* hTb = hT + (size_t)bh * HOn * Nn;

    int c0 = 2 * lane;
    float* edw = &ed_lds[w][0];

    f32x4 acc[4] = {{0.f, 0.f, 0.f, 0.f}, {0.f, 0.f, 0.f, 0.f},
                    {0.f, 0.f, 0.f, 0.f}, {0.f, 0.f, 0.f, 0.f}};
    f32x4 accl = {0.f, 0.f, 0.f, 0.f};  // l row-sums via MFMA with B = ones
    bf16x8 ONES;
    {
        short o = (short)0x3F80;  // bf16 1.0
        ONES = (bf16x8){o, o, o, o, o, o, o, o};
    }

    // ed sentinel row (a = 0): exp2(-3e38 * anything-leaky) == 0 -> masked p = 0
    edw[c0] = -3e38f;
    edw[c0 + 1] = -3e38f;

    // prologue: chunk 0's full 16 adj rows + ed into regs
    unsigned adjC[16], adjN[16];
#pragma unroll
    for (int r = 0; r < 16; r++)
        adjC[r] = *(const unsigned short*)(adj_base + (size_t)r * Nn + c0);
    float2 edr[Tn];
#pragma unroll
    for (int t = 0; t < Tn; t++) edr[t] = *(const float2*)(edst + t * Nn + c0);

    // es2[hh][row][a] staging (waves 0-3): slot 0 = 0.0 sentinel, slots 1..5 = e_src
    if (w < 4) {
        const float* esrc = e_src + (size_t)bh * Tn * Nn;
#pragma unroll
        for (int idx = lane; idx < 96; idx += 64) {
            int t = idx >> 4, row = idx & 15;
            es2[w][row][t] = t ? esrc[(t - 1) * Nn + i0 + row] : 0.f;
        }
    }
    __syncthreads();

// pass-1: p = exp2(leakyrelu(es2[row][a] + ed_lds[a][col])), sentinels make masked -> 0.
// es: LDS broadcast (6 distinct banks, conflict-free); ed: EDS=128 gather (2-way, free).
#define P1ROW(ROW, AV)                                                          \
    {                                                                           \
        int a0 = (int)((AV) & 0xFFu);                                           \
        int a1 = (int)((AV) >> 8);                                              \
        float e0 = es2[hh][ROW][a0];                                            \
        float e1 = es2[hh][ROW][a1];                                            \
        float d0 = edw[a0 * EDS + c0];                                          \
        float d1 = edw[a1 * EDS + c0 + 1];                                      \
        float x0 = e0 + d0; x0 = fmaxf(x0, 0.01f * x0);                         \
        float x1 = e1 + d1; x1 = fmaxf(x1, 0.01f * x1);                         \
        float p0 = fast_exp2(x0);                                               \
        float p1 = fast_exp2(x1);                                               \
        __hip_bfloat162 pp = __float22bfloat162_rn(make_float2(p0, p1));        \
        unsigned pu; __builtin_memcpy(&pu, &pp, 4);                             \
        *(unsigned*)(&p_lds[w][ROW][2 * lane]) = pu;                            \
    }

#pragma unroll 1
    for (int c = 0; c < 4; c++) {
        int jc = c * 128;  // relative to J0
        // commit this chunk's ed regs to LDS rows 1..5 (reads edr loaded a full chunk ago)
#pragma unroll
        for (int t = 0; t < Tn; t++) {
            int wi = (t + 1) * EDS + c0;
            edw[wi] = edr[t].x;
            edw[wi + 1] = edr[t].y;
        }
        // R20: issue next chunk's FULL adj row set + ed now — consumed next iteration,
        // so pass-1 + PV of this chunk (~600+cy) cover the L2/HBM latency.
        if (c < 3) {
#pragma unroll
            for (int r = 0; r < 16; r++)
                adjN[r] = *(const unsigned short*)(adj_base + (size_t)r * Nn + jc + 128 + c0);
#pragma unroll
            for (int t = 0; t < Tn; t++)
                edr[t] = *(const float2*)(edst + t * Nn + jc + 128 + c0);
        }
        // pass-1 over all 16 rows from adjC regs
#pragma unroll
        for (int r = 0; r < 16; r++) P1ROW(r, adjC[r]);
        // PV via MFMA: A = P (own-wave LDS, b128); per-k hT loads (R18 schedule, measured
        // best); 5th tile (B=ones) accumulates l row-sums
#pragma unroll
        for (int k = 0; k < 4; k++) {
            bf16x8 Afr = *(const bf16x8*)(&p_lds[w][l15][k * 32 + quad * 8]);
            accl = __builtin_amdgcn_mfma_f32_16x16x32_bf16(Afr, ONES, accl, 0, 0, 0);
#pragma unroll
            for (int et = 0; et < 4; et++) {
                bf16x8 Bf = *(const bf16x8*)(hTb + (size_t)(et * 16 + l15) * Nn + J0 + jc + k * 32 + quad * 8);
                acc[et] = __builtin_amdgcn_mfma_f32_16x16x32_bf16(Afr, Bf, acc[et], 0, 0, 0);
            }
        }
        // promote prefetched adj
        if (c < 3) {
#pragma unroll
            for (int r = 0; r < 16; r++) adjC[r] = adjN[r];
        }
    }
#undef P1ROW

    // l: accl[reg] (any l15 col) = row-sum for row quad*4+reg
    if (l15 == 0) {
#pragma unroll
        for (int reg = 0; reg < 4; reg++) l_lds[w][quad * 4 + reg] = accl[reg];
    }
    __syncthreads();  // all waves done with p_lds (MFMA reads) before macc overlay
    if (w >= 4) {
#pragma unroll
        for (int et = 0; et < 4; et++)
#pragma unroll
            for (int reg = 0; reg < 4; reg++)
                macc[((hh * 16) + quad * 4 + reg) * 64 + et * 16 + l15] = acc[et][reg];
    }
    __syncthreads();
    if (w >= 4) return;

    // merge + epilogue: /l, +bias, relu, +h, LayerNorm over HO, store f32
    float bv[4], gv[4], bev[4];
#pragma unroll
    for (int et = 0; et < 4; et++) {
        int e = et * 16 + l15;
        bv[et] = bias[hh * HOn + e];
        gv[et] = gamma[hh * HOn + e];
        bev[et] = beta[hh * HOn + e];
    }
#pragma unroll
    for (int reg = 0; reg < 4; reg++) {
        int r = quad * 4 + reg;
        int i = i0 + r;
        float lw = l_lds[w][r] + l_lds[w + 4][r];
        float linv = 1.f / fmaxf(lw, 1e-30f);
        float dv[4];
        float s = 0.f, ss = 0.f;
#pragma unroll
        for (int et = 0; et < 4; et++) {
            int e = et * 16 + l15;
            float v = (acc[et][reg] + macc[((hh * 16) + r) * 64 + e]) * linv + bv[et];
            v = (v > 0.f) ? v : 0.f;
            v += b2f(hTb[(size_t)e * Nn + i]);  // residual h
            dv[et] = v;
            s += v;
            ss += v * v;
        }
#pragma unroll
        for (int off = 8; off; off >>= 1) {
            s += __shfl_xor(s, off);
            ss += __shfl_xor(ss, off);
        }
        float mean = s * (1.f / 64.f);
        float var = ss * (1.f / 64.f) - mean * mean;
        float rstd = rsqrtf(var + 1e-6f);
#pragma unroll
        for (int et = 0; et < 4; et++) {
            int e = et * 16 + l15;
            float o = (dv[et] - mean) * rstd * gv[et] + bev[et];
            out[((size_t)(b * Nn + i)) * (Hn * HOn) + hh * HOn + e] = o;
        }
    }
}

extern "C" void kernel_launch(void* const* d_in, const int* in_sizes, int n_in,
                              void* d_out, int out_size, void* d_ws, size_t ws_size,
                              hipStream_t stream) {
    const float* X = (const float*)d_in[0];        // nodes_embed f32 [B,N,D]
    const int* adj = (const int*)d_in[1];          // node_adj int32 [B,N,N]
    const float* W = (const float*)d_in[2];        // [H,D,HO] f32
    const float* a_src = (const float*)d_in[3];    // [H,T,HO] f32
    const float* a_dst = (const float*)d_in[4];    // [H,T,HO] f32
    const float* bias = (const float*)d_in[5];     // [H,HO] f32
    const float* gamma = (const float*)d_in[6];    // [H,HO] f32
    const float* beta = (const float*)d_in[7];     // [H,HO] f32
    float* out = (float*)d_out;                    // [B,N,H*HO] f32

    char* ws = (char*)d_ws;
    size_t off = 0;
    unsigned short* hT = (unsigned short*)(ws + off);  off += (size_t)Bn * Hn * Nn * HOn * 2;  // 4 MB
    unsigned short* WT = (unsigned short*)(ws + off);  off += (size_t)Hn * WTR * Dn * 2;       // 160 KB
    float* e_src = (float*)(ws + off);                 off += (size_t)Bn * Hn * Tn * Nn * 4;   // 640 KB
    float* e_dst = (float*)(ws + off);                 off += (size_t)Bn * Hn * Tn * Nn * 4;   // 640 KB
    unsigned char* adjp = (unsigned char*)(ws + off);  off += (size_t)Bn * Nn * Nn;            // 8 MB

    if (ws_size < off) {
        k_signal<<<(out_size + 255) / 256, 256, 0, stream>>>(out, out_size);
        return;
    }

    k_transpose_w<<<Hn * (Dn / 64), 256, 0, stream>>>(W, a_src, a_dst, WT);
    k_proj<<<Bn * (Nn / 16), 256, 0, stream>>>(X, WT, adj, hT, e_src, e_dst, (unsigned*)adjp);
    k_attn<<<Bn * (Nn / 16), 512, 0, stream>>>(adjp, e_src, e_dst, hT, bias, gamma, beta, out);
}